// Round 5
// baseline (234.123 us; speedup 1.0000x reference)
//
#include <hip/hip_runtime.h>
#include <hip/hip_bf16.h>

// B=2, T=2048, C=1024, H=16, Dh=64
// ws layout (bytes), total 44,040,192:
//   xb   [4096x1024] bf16 @ 0          -- reused as vt [2][16][64][2048] after qkv GEMM
//   wat  [3072x1024] bf16 @ 8388608    -- reused as yb [4096x1024] bf16 after qkv GEMM
//   qkv  [4096x3072] bf16 @ 16777216   (Q columns pre-scaled by (1/8)*log2(e))
//   wpt  [1024x1024] bf16 @ 41943040

typedef __attribute__((ext_vector_type(8))) __bf16 bf16x8;
typedef __attribute__((ext_vector_type(4))) float  floatx4;
typedef __attribute__((ext_vector_type(4))) float  fvec4;
typedef __attribute__((ext_vector_type(4))) short  short4v;

#define MFMA16(a, b, c) __builtin_amdgcn_mfma_f32_16x16x32_bf16(a, b, c, 0, 0, 0)

using as1v = const __attribute__((address_space(1))) void;
using as3v = __attribute__((address_space(3))) void;
__device__ __forceinline__ void async16(const void* g, void* l) {
  __builtin_amdgcn_global_load_lds((as1v*)g, (as3v*)l, 16, 0, 0);
}

__device__ inline void store_out(float* p, float v) { *p = v; }
__device__ inline void store_out(__hip_bfloat16* p, float v) { *p = __float2bfloat16(v); }

// ---------------- fused prep: cast x, transpose+cast both weights ----------------
__global__ __launch_bounds__(256) void prep_kernel(const float* __restrict__ x,
                                                   const float* __restrict__ w_attn,
                                                   const float* __restrict__ w_proj,
                                                   __hip_bfloat16* __restrict__ xb,
                                                   __hip_bfloat16* __restrict__ wat,
                                                   __hip_bfloat16* __restrict__ wpt) {
  __shared__ float tile[32][33];
  const int bid = blockIdx.x, tid = threadIdx.x;
  if (bid < 4096) {  // cast x -> bf16 (4 elems/thread)
    const int i = (bid * 256 + tid) * 4;
    fvec4 v = *(const fvec4*)(x + i);
    union { short4v s; __hip_bfloat16 h[4]; } u;
#pragma unroll
    for (int j = 0; j < 4; ++j) u.h[j] = __float2bfloat16(v[j]);
    *(short4v*)((short*)xb + i) = u.s;
    return;
  }
  const float* in;
  __hip_bfloat16* out;
  int rows, cols, bx, by;
  if (bid < 4096 + 3072) {
    const int b2 = bid - 4096;
    in = w_attn; out = wat; rows = 1024; cols = 3072; bx = b2 % 96; by = b2 / 96;
  } else {
    const int b2 = bid - 7168;
    in = w_proj; out = wpt; rows = 1024; cols = 1024; bx = b2 % 32; by = b2 / 32;
  }
  const int tx = tid & 31, ty = tid >> 5;
  const int c0 = bx * 32, r0 = by * 32;
#pragma unroll
  for (int i = 0; i < 32; i += 8)
    tile[ty + i][tx] = in[(long)(r0 + ty + i) * cols + c0 + tx];
  __syncthreads();
#pragma unroll
  for (int i = 0; i < 32; i += 8)
    out[(long)(c0 + ty + i) * rows + r0 + tx] = __float2bfloat16(tile[tx][ty + i]);
}

// ------------- V^T extraction: vt[b][h][d][t] = qkv[b*T+t][2048+h*64+d] -------------
__global__ __launch_bounds__(256) void vt_kernel(const __hip_bfloat16* __restrict__ qkv,
                                                 __hip_bfloat16* __restrict__ vt) {
  __shared__ __align__(16) __hip_bfloat16 tile[64 * 64];
  const int tid = threadIdx.x;
  const int tt0 = blockIdx.x * 64, h = blockIdx.y, b = blockIdx.z;
  const long bh = (long)b * 16 + h;
#pragma unroll
  for (int it = 0; it < 2; ++it) {
    const int c = it * 256 + tid;
    const int row = c >> 3, cg = c & 7;
    const int pg = cg ^ ((row >> 3) & 7);
    *(bf16x8*)(tile + row * 64 + pg * 8) =
        *(const bf16x8*)(qkv + ((long)b * 2048 + tt0 + row) * 3072 + 2048 + h * 64 + cg * 8);
  }
  __syncthreads();
#pragma unroll
  for (int it = 0; it < 2; ++it) {
    const int c = it * 256 + tid;
    const int dr = c >> 3, tg = c & 7;
    union { bf16x8 v; __hip_bfloat16 e[8]; } u;
    const int pg = (dr >> 3) ^ tg;
#pragma unroll
    for (int j = 0; j < 8; ++j)
      u.e[j] = tile[(tg * 8 + j) * 64 + pg * 8 + (dr & 7)];
    *(bf16x8*)(vt + (bh * 64 + dr) * 2048 + tt0 + tg * 8) = u.v;
  }
}

// ------------- GEMM 128x128: C = A * Bt^T, dbuf global_load_lds, 1 barrier/iter -------------
// qlim/qscale: columns < qlim are scaled by qscale in the epilogue (Q pre-scaling).
template <typename OutT>
__global__ __launch_bounds__(256) void gemm_bt_kernel(const __hip_bfloat16* __restrict__ A,
                                                      const __hip_bfloat16* __restrict__ Bt,
                                                      OutT* __restrict__ C,
                                                      int M, int N, int K,
                                                      float qscale, int qlim) {
  __shared__ __align__(16) __hip_bfloat16 As[2][128 * 32];
  __shared__ __align__(16) __hip_bfloat16 Bs[2][128 * 32];
  const int tid = threadIdx.x;
  const int lane = tid & 63, wv = tid >> 6;
  const int l15 = lane & 15, quad = lane >> 4;
  const int wm = wv >> 1, wn = wv & 1;
  const long m0 = (long)blockIdx.y * 128, n0 = (long)blockIdx.x * 128;
  floatx4 acc[4][4] = {};
  const int nk = K >> 5;

  auto issue = [&](int kt, int p) {
    const int k0 = kt << 5;
#pragma unroll
    for (int it = 0; it < 2; ++it) {
      const int c = it * 256 + tid;
      const int row = c >> 2;
      const int lcg = (c & 3) ^ ((row >> 1) & 3);
      async16(A + (m0 + row) * K + k0 + lcg * 8, (char*)&As[p][0] + c * 16);
      async16(Bt + (n0 + row) * K + k0 + lcg * 8, (char*)&Bs[p][0] + c * 16);
    }
  };

  issue(0, 0);
  for (int kt = 0; kt < nk; ++kt) {
    const int p = kt & 1;
    __syncthreads();
    if (kt + 1 < nk) issue(kt + 1, p ^ 1);
    bf16x8 af[4], bfr[4];
#pragma unroll
    for (int t = 0; t < 4; ++t) {
      const int ar = wm * 64 + t * 16 + l15;
      const int br = wn * 64 + t * 16 + l15;
      af[t]  = *(const bf16x8*)(&As[p][ar * 32 + (quad ^ ((ar >> 1) & 3)) * 8]);
      bfr[t] = *(const bf16x8*)(&Bs[p][br * 32 + (quad ^ ((br >> 1) & 3)) * 8]);
    }
#pragma unroll
    for (int mt = 0; mt < 4; ++mt)
#pragma unroll
      for (int nt = 0; nt < 4; ++nt)
        acc[mt][nt] = MFMA16(af[mt], bfr[nt], acc[mt][nt]);
  }
#pragma unroll
  for (int mt = 0; mt < 4; ++mt)
#pragma unroll
    for (int nt = 0; nt < 4; ++nt)
#pragma unroll
      for (int r = 0; r < 4; ++r) {
        const long row = m0 + wm * 64 + mt * 16 + quad * 4 + r;
        const long col = n0 + wn * 64 + nt * 16 + l15;
        float v = acc[mt][nt][r];
        if ((int)col < qlim) v *= qscale;
        store_out(C + row * N + col, v);
      }
}

// ------------- GEMM 128x64 (for proj: more blocks, better latency hiding) -------------
template <typename OutT>
__global__ __launch_bounds__(256) void gemm_bt64_kernel(const __hip_bfloat16* __restrict__ A,
                                                        const __hip_bfloat16* __restrict__ Bt,
                                                        OutT* __restrict__ C,
                                                        int M, int N, int K) {
  __shared__ __align__(16) __hip_bfloat16 As[2][128 * 32];
  __shared__ __align__(16) __hip_bfloat16 Bs[2][64 * 32];
  const int tid = threadIdx.x;
  const int lane = tid & 63, wv = tid >> 6;
  const int l15 = lane & 15, quad = lane >> 4;
  const int wm = wv >> 1, wn = wv & 1;
  const long m0 = (long)blockIdx.y * 128, n0 = (long)blockIdx.x * 64;
  floatx4 acc[4][2] = {};
  const int nk = K >> 5;

  auto issue = [&](int kt, int p) {
    const int k0 = kt << 5;
#pragma unroll
    for (int it = 0; it < 2; ++it) {
      const int c = it * 256 + tid;
      const int row = c >> 2;
      const int lcg = (c & 3) ^ ((row >> 1) & 3);
      async16(A + (m0 + row) * K + k0 + lcg * 8, (char*)&As[p][0] + c * 16);
    }
    {
      const int c = tid;
      const int row = c >> 2;
      const int lcg = (c & 3) ^ ((row >> 1) & 3);
      async16(Bt + (n0 + row) * K + k0 + lcg * 8, (char*)&Bs[p][0] + c * 16);
    }
  };

  issue(0, 0);
  for (int kt = 0; kt < nk; ++kt) {
    const int p = kt & 1;
    __syncthreads();
    if (kt + 1 < nk) issue(kt + 1, p ^ 1);
    bf16x8 af[4], bfr[2];
#pragma unroll
    for (int t = 0; t < 4; ++t) {
      const int ar = wm * 64 + t * 16 + l15;
      af[t] = *(const bf16x8*)(&As[p][ar * 32 + (quad ^ ((ar >> 1) & 3)) * 8]);
    }
#pragma unroll
    for (int t = 0; t < 2; ++t) {
      const int br = wn * 32 + t * 16 + l15;
      bfr[t] = *(const bf16x8*)(&Bs[p][br * 32 + (quad ^ ((br >> 1) & 3)) * 8]);
    }
#pragma unroll
    for (int mt = 0; mt < 4; ++mt)
#pragma unroll
      for (int nt = 0; nt < 2; ++nt)
        acc[mt][nt] = MFMA16(af[mt], bfr[nt], acc[mt][nt]);
  }
#pragma unroll
  for (int mt = 0; mt < 4; ++mt)
#pragma unroll
    for (int nt = 0; nt < 2; ++nt)
#pragma unroll
      for (int r = 0; r < 4; ++r) {
        const long row = m0 + wm * 64 + mt * 16 + quad * 4 + r;
        const long col = n0 + wn * 32 + nt * 16 + l15;
        store_out(C + row * N + col, acc[mt][nt][r]);
      }
}

// ------------- unpaired flash attention: 1 q-tile(64)/block, grid 1024 -------------
// K/Vt staged via global_load_lds into XOR-swizzled 64x64 dbuf; fixed-max softmax
// (Q pre-scaled by (1/8)log2e in the qkv GEMM); masked diagonal iteration peeled;
// row-sum via constant-ones B-fragment. LDS = 40960 B -> 4 blocks/CU.
__global__ __launch_bounds__(256) void attn_kernel(const __hip_bfloat16* __restrict__ qkv,
                                                   const __hip_bfloat16* __restrict__ vtg,
                                                   __hip_bfloat16* __restrict__ y) {
  __shared__ __align__(16) __hip_bfloat16 Ks[2][64 * 64];
  __shared__ __align__(16) __hip_bfloat16 Vt[2][64 * 64];
  __shared__ __align__(16) __hip_bfloat16 Ps[4 * 16 * 64];
  const int tid = threadIdx.x;
  const int lane = tid & 63, wv = tid >> 6;
  const int l15 = lane & 15, quad = lane >> 4;
  const int qt = blockIdx.x, h = blockIdx.y, b = blockIdx.z;
  const int q0 = qt * 64;
  const long bh = (long)b * 16 + h;
  const long RS = 3072;

  auto issue = [&](int kt, int p) {
    const int kb = kt * 64;
#pragma unroll
    for (int it = 0; it < 2; ++it) {
      const int c = it * 256 + tid;
      const int row = c >> 3;
      const int cg = (c & 7) ^ (row & 7);
      async16(qkv + ((long)b * 2048 + kb + row) * RS + 1024 + h * 64 + cg * 8,
              (char*)&Ks[p][0] + c * 16);
      async16(vtg + (bh * 64 + row) * 2048 + kb + cg * 8, (char*)&Vt[p][0] + c * 16);
    }
  };

  // Q A-fragments (pre-scaled in qkv GEMM epilogue)
  bf16x8 aq0, aq1;
  {
    const __hip_bfloat16* qp = qkv + ((long)b * 2048 + q0 + wv * 16 + l15) * RS + h * 64 + quad * 8;
    aq0 = *(const bf16x8*)qp;
    aq1 = *(const bf16x8*)(qp + 32);
  }
  union { bf16x8 v; __hip_bfloat16 e[8]; } uo;
#pragma unroll
  for (int j = 0; j < 8; ++j) uo.e[j] = __float2bfloat16(1.0f);
  const bf16x8 ones = uo.v;

  floatx4 o[4] = {}, o4 = {};
  __hip_bfloat16* Psw = Ps + wv * 1024;  // wave-private 16x64, XOR-swizzled

  auto compute = [&](int kt, int p, bool mask) {
    const int kb = kt * 64;
    bf16x8 kf[4][2], vf[4][2];
#pragma unroll
    for (int nt = 0; nt < 4; ++nt) {
      const int row = nt * 16 + l15;
      const int s0 = (quad ^ (row & 7)) * 8, s1 = ((quad + 4) ^ (row & 7)) * 8;
      kf[nt][0] = *(const bf16x8*)(&Ks[p][row * 64 + s0]);
      kf[nt][1] = *(const bf16x8*)(&Ks[p][row * 64 + s1]);
      vf[nt][0] = *(const bf16x8*)(&Vt[p][row * 64 + s0]);
      vf[nt][1] = *(const bf16x8*)(&Vt[p][row * 64 + s1]);
    }
    floatx4 s[4] = {};
#pragma unroll
    for (int nt = 0; nt < 4; ++nt) {
      s[nt] = MFMA16(aq0, kf[nt][0], s[nt]);
      s[nt] = MFMA16(aq1, kf[nt][1], s[nt]);
    }
    // fixed-max softmax; Ps layout: row=quad*4+r, col=nt*16+l15, chunk-XOR swizzle
#pragma unroll
    for (int nt = 0; nt < 4; ++nt)
#pragma unroll
      for (int r = 0; r < 4; ++r) {
        float pv = exp2f(s[nt][r]);
        if (mask && (kb + nt * 16 + l15 > q0 + wv * 16 + quad * 4 + r)) pv = 0.f;
        const int row = quad * 4 + r;
        const int pg = (nt * 2 + (l15 >> 3)) ^ (row & 7);
        Psw[row * 64 + pg * 8 + (l15 & 7)] = __float2bfloat16(pv);
      }
    const int m7 = l15 & 7;
    const __hip_bfloat16* pb = Psw + l15 * 64;
    const bf16x8 p0 = *(const bf16x8*)(pb + (quad ^ m7) * 8);
    const bf16x8 p1 = *(const bf16x8*)(pb + ((quad + 4) ^ m7) * 8);
#pragma unroll
    for (int nt = 0; nt < 4; ++nt) {
      o[nt] = MFMA16(p0, vf[nt][0], o[nt]);
      o[nt] = MFMA16(p1, vf[nt][1], o[nt]);
    }
    o4 = MFMA16(p0, ones, o4);
    o4 = MFMA16(p1, ones, o4);
  };

  issue(0, 0);
  for (int kt = 0; kt < qt; ++kt) {
    const int p = kt & 1;
    __syncthreads();
    issue(kt + 1, p ^ 1);
    compute(kt, p, false);
  }
  {
    const int p = qt & 1;
    __syncthreads();
    compute(qt, p, true);
  }

  // epilogue: every lane of o4 holds its row-sum (ones B-frag)
#pragma unroll
  for (int r = 0; r < 4; ++r) {
    const float inv = 1.0f / o4[r];
    const long t = (long)b * 2048 + q0 + wv * 16 + quad * 4 + r;
#pragma unroll
    for (int nt = 0; nt < 4; ++nt)
      y[t * 1024 + h * 64 + nt * 16 + l15] = __float2bfloat16(o[nt][r] * inv);
  }
}

extern "C" void kernel_launch(void* const* d_in, const int* in_sizes, int n_in,
                              void* d_out, int out_size, void* d_ws, size_t ws_size,
                              hipStream_t stream) {
  const float* x      = (const float*)d_in[0];
  const float* w_attn = (const float*)d_in[1];
  const float* w_proj = (const float*)d_in[2];
  float* out = (float*)d_out;
  char* ws = (char*)d_ws;
  __hip_bfloat16* xb   = (__hip_bfloat16*)(ws);               // then vt
  __hip_bfloat16* wat  = (__hip_bfloat16*)(ws + 8388608);     // then yb
  __hip_bfloat16* qkvb = (__hip_bfloat16*)(ws + 16777216);
  __hip_bfloat16* wpt  = (__hip_bfloat16*)(ws + 41943040);
  __hip_bfloat16* vtg  = xb;
  __hip_bfloat16* yb   = wat;
  const float SC = 0.18033688011112042f;  // (1/8) * log2(e)

  // prep: cast x (4096 blocks) + transpose w_attn (3072) + transpose w_proj (1024)
  prep_kernel<<<8192, 256, 0, stream>>>(x, w_attn, w_proj, xb, wat, wpt);
  // qkv = x @ w_attn, Q columns pre-scaled by SC
  gemm_bt_kernel<__hip_bfloat16><<<dim3(24, 32), 256, 0, stream>>>(xb, wat, qkvb, 4096, 3072, 1024, SC, 1024);
  // V^T (overwrites xb -- dead after the qkv GEMM)
  vt_kernel<<<dim3(32, 16, 2), 256, 0, stream>>>(qkvb, vtg);
  // attention (writes yb over wat -- dead after the qkv GEMM)
  attn_kernel<<<dim3(32, 16, 2), 256, 0, stream>>>(qkvb, vtg, yb);
  // out = y @ w_proj
  gemm_bt64_kernel<float><<<dim3(16, 32), 256, 0, stream>>>(yb, wpt, out, 4096, 1024, 1024);
}

// Round 6
// 186.130 us; speedup vs baseline: 1.2578x; 1.2578x over previous
//
#include <hip/hip_runtime.h>
#include <hip/hip_bf16.h>

// B=2, T=2048, C=1024, H=16, Dh=64
// ws layout (bytes), total 44,040,192:
//   xb   [4096x1024] bf16 @ 0          -- reused as vt [2][16][64][2048] after qkv GEMM
//   wat  [3072x1024] bf16 @ 8388608    -- reused as yb [4096x1024] bf16 after qkv GEMM
//   qkv  [4096x3072] bf16 @ 16777216   (Q columns pre-scaled by (1/8)*log2(e))
//   wpt  [1024x1024] bf16 @ 41943040

typedef __attribute__((ext_vector_type(8))) __bf16 bf16x8;
typedef __attribute__((ext_vector_type(4))) float  floatx4;
typedef __attribute__((ext_vector_type(4))) float  fvec4;
typedef __attribute__((ext_vector_type(4))) short  short4v;

#define MFMA16(a, b, c) __builtin_amdgcn_mfma_f32_16x16x32_bf16(a, b, c, 0, 0, 0)

using as1v = const __attribute__((address_space(1))) void;
using as3v = __attribute__((address_space(3))) void;
__device__ __forceinline__ void async16(const void* g, void* l) {
  __builtin_amdgcn_global_load_lds((as1v*)g, (as3v*)l, 16, 0, 0);
}

__device__ inline void store_out(float* p, float v) { *p = v; }
__device__ inline void store_out(__hip_bfloat16* p, float v) { *p = __float2bfloat16(v); }

// ---------------- fused prep: cast x, transpose+cast both weights ----------------
__global__ __launch_bounds__(256) void prep_kernel(const float* __restrict__ x,
                                                   const float* __restrict__ w_attn,
                                                   const float* __restrict__ w_proj,
                                                   __hip_bfloat16* __restrict__ xb,
                                                   __hip_bfloat16* __restrict__ wat,
                                                   __hip_bfloat16* __restrict__ wpt) {
  __shared__ float tile[32][33];
  const int bid = blockIdx.x, tid = threadIdx.x;
  if (bid < 4096) {  // cast x -> bf16 (4 elems/thread)
    const int i = (bid * 256 + tid) * 4;
    fvec4 v = *(const fvec4*)(x + i);
    union { short4v s; __hip_bfloat16 h[4]; } u;
#pragma unroll
    for (int j = 0; j < 4; ++j) u.h[j] = __float2bfloat16(v[j]);
    *(short4v*)((short*)xb + i) = u.s;
    return;
  }
  const float* in;
  __hip_bfloat16* out;
  int rows, cols, bx, by;
  if (bid < 4096 + 3072) {
    const int b2 = bid - 4096;
    in = w_attn; out = wat; rows = 1024; cols = 3072; bx = b2 % 96; by = b2 / 96;
  } else {
    const int b2 = bid - 7168;
    in = w_proj; out = wpt; rows = 1024; cols = 1024; bx = b2 % 32; by = b2 / 32;
  }
  const int tx = tid & 31, ty = tid >> 5;
  const int c0 = bx * 32, r0 = by * 32;
#pragma unroll
  for (int i = 0; i < 32; i += 8)
    tile[ty + i][tx] = in[(long)(r0 + ty + i) * cols + c0 + tx];
  __syncthreads();
#pragma unroll
  for (int i = 0; i < 32; i += 8)
    out[(long)(c0 + ty + i) * rows + r0 + tx] = __float2bfloat16(tile[tx][ty + i]);
}

// ------------- V^T extraction: vt[b][h][d][t] = qkv[b*T+t][2048+h*64+d] -------------
__global__ __launch_bounds__(256) void vt_kernel(const __hip_bfloat16* __restrict__ qkv,
                                                 __hip_bfloat16* __restrict__ vt) {
  __shared__ __align__(16) __hip_bfloat16 tile[64 * 64];
  const int tid = threadIdx.x;
  const int tt0 = blockIdx.x * 64, h = blockIdx.y, b = blockIdx.z;
  const long bh = (long)b * 16 + h;
#pragma unroll
  for (int it = 0; it < 2; ++it) {
    const int c = it * 256 + tid;
    const int row = c >> 3, cg = c & 7;
    const int pg = cg ^ ((row >> 3) & 7);
    *(bf16x8*)(tile + row * 64 + pg * 8) =
        *(const bf16x8*)(qkv + ((long)b * 2048 + tt0 + row) * 3072 + 2048 + h * 64 + cg * 8);
  }
  __syncthreads();
#pragma unroll
  for (int it = 0; it < 2; ++it) {
    const int c = it * 256 + tid;
    const int dr = c >> 3, tg = c & 7;
    union { bf16x8 v; __hip_bfloat16 e[8]; } u;
    const int pg = (dr >> 3) ^ tg;
#pragma unroll
    for (int j = 0; j < 8; ++j)
      u.e[j] = tile[(tg * 8 + j) * 64 + pg * 8 + (dr & 7)];
    *(bf16x8*)(vt + (bh * 64 + dr) * 2048 + tt0 + tg * 8) = u.v;
  }
}

// ------------- GEMM 128x128: C = A * Bt^T, dbuf global_load_lds, 1 barrier/iter -------------
template <typename OutT>
__global__ __launch_bounds__(256) void gemm_bt_kernel(const __hip_bfloat16* __restrict__ A,
                                                      const __hip_bfloat16* __restrict__ Bt,
                                                      OutT* __restrict__ C,
                                                      int M, int N, int K,
                                                      float qscale, int qlim) {
  __shared__ __align__(16) __hip_bfloat16 As[2][128 * 32];
  __shared__ __align__(16) __hip_bfloat16 Bs[2][128 * 32];
  const int tid = threadIdx.x;
  const int lane = tid & 63, wv = tid >> 6;
  const int l15 = lane & 15, quad = lane >> 4;
  const int wm = wv >> 1, wn = wv & 1;
  const long m0 = (long)blockIdx.y * 128, n0 = (long)blockIdx.x * 128;
  floatx4 acc[4][4] = {};
  const int nk = K >> 5;

  auto issue = [&](int kt, int p) {
    const int k0 = kt << 5;
#pragma unroll
    for (int it = 0; it < 2; ++it) {
      const int c = it * 256 + tid;
      const int row = c >> 2;
      const int lcg = (c & 3) ^ ((row >> 1) & 3);
      async16(A + (m0 + row) * K + k0 + lcg * 8, (char*)&As[p][0] + c * 16);
      async16(Bt + (n0 + row) * K + k0 + lcg * 8, (char*)&Bs[p][0] + c * 16);
    }
  };

  issue(0, 0);
  for (int kt = 0; kt < nk; ++kt) {
    const int p = kt & 1;
    __syncthreads();
    if (kt + 1 < nk) issue(kt + 1, p ^ 1);
    bf16x8 af[4], bfr[4];
#pragma unroll
    for (int t = 0; t < 4; ++t) {
      const int ar = wm * 64 + t * 16 + l15;
      const int br = wn * 64 + t * 16 + l15;
      af[t]  = *(const bf16x8*)(&As[p][ar * 32 + (quad ^ ((ar >> 1) & 3)) * 8]);
      bfr[t] = *(const bf16x8*)(&Bs[p][br * 32 + (quad ^ ((br >> 1) & 3)) * 8]);
    }
#pragma unroll
    for (int mt = 0; mt < 4; ++mt)
#pragma unroll
      for (int nt = 0; nt < 4; ++nt)
        acc[mt][nt] = MFMA16(af[mt], bfr[nt], acc[mt][nt]);
  }
#pragma unroll
  for (int mt = 0; mt < 4; ++mt)
#pragma unroll
    for (int nt = 0; nt < 4; ++nt)
#pragma unroll
      for (int r = 0; r < 4; ++r) {
        const long row = m0 + wm * 64 + mt * 16 + quad * 4 + r;
        const long col = n0 + wn * 64 + nt * 16 + l15;
        float v = acc[mt][nt][r];
        if ((int)col < qlim) v *= qscale;
        store_out(C + row * N + col, v);
      }
}

// ------------- GEMM 128x64 (proj: more blocks, better latency hiding) -------------
template <typename OutT>
__global__ __launch_bounds__(256) void gemm_bt64_kernel(const __hip_bfloat16* __restrict__ A,
                                                        const __hip_bfloat16* __restrict__ Bt,
                                                        OutT* __restrict__ C,
                                                        int M, int N, int K) {
  __shared__ __align__(16) __hip_bfloat16 As[2][128 * 32];
  __shared__ __align__(16) __hip_bfloat16 Bs[2][64 * 32];
  const int tid = threadIdx.x;
  const int lane = tid & 63, wv = tid >> 6;
  const int l15 = lane & 15, quad = lane >> 4;
  const int wm = wv >> 1, wn = wv & 1;
  const long m0 = (long)blockIdx.y * 128, n0 = (long)blockIdx.x * 64;
  floatx4 acc[4][2] = {};
  const int nk = K >> 5;

  auto issue = [&](int kt, int p) {
    const int k0 = kt << 5;
#pragma unroll
    for (int it = 0; it < 2; ++it) {
      const int c = it * 256 + tid;
      const int row = c >> 2;
      const int lcg = (c & 3) ^ ((row >> 1) & 3);
      async16(A + (m0 + row) * K + k0 + lcg * 8, (char*)&As[p][0] + c * 16);
    }
    {
      const int c = tid;
      const int row = c >> 2;
      const int lcg = (c & 3) ^ ((row >> 1) & 3);
      async16(Bt + (n0 + row) * K + k0 + lcg * 8, (char*)&Bs[p][0] + c * 16);
    }
  };

  issue(0, 0);
  for (int kt = 0; kt < nk; ++kt) {
    const int p = kt & 1;
    __syncthreads();
    if (kt + 1 < nk) issue(kt + 1, p ^ 1);
    bf16x8 af[4], bfr[2];
#pragma unroll
    for (int t = 0; t < 4; ++t) {
      const int ar = wm * 64 + t * 16 + l15;
      af[t] = *(const bf16x8*)(&As[p][ar * 32 + (quad ^ ((ar >> 1) & 3)) * 8]);
    }
#pragma unroll
    for (int t = 0; t < 2; ++t) {
      const int br = wn * 32 + t * 16 + l15;
      bfr[t] = *(const bf16x8*)(&Bs[p][br * 32 + (quad ^ ((br >> 1) & 3)) * 8]);
    }
#pragma unroll
    for (int mt = 0; mt < 4; ++mt)
#pragma unroll
      for (int nt = 0; nt < 2; ++nt)
        acc[mt][nt] = MFMA16(af[mt], bfr[nt], acc[mt][nt]);
  }
#pragma unroll
  for (int mt = 0; mt < 4; ++mt)
#pragma unroll
    for (int nt = 0; nt < 2; ++nt)
#pragma unroll
      for (int r = 0; r < 4; ++r) {
        const long row = m0 + wm * 64 + mt * 16 + quad * 4 + r;
        const long col = n0 + wn * 32 + nt * 16 + l15;
        store_out(C + row * N + col, acc[mt][nt][r]);
      }
}

// ------------- paired-tile flash attention, S^T-swapped MFMA -------------
// block = (pair pt, head h, batch b): q-tiles qtA=pt, qtB=31-pt -> 33 active tiles, uniform.
// S^T = K Q^T (A=K frag, B=Q frag -- same registers as the S form!), so exp2 output is
// already P^T in C-layout (lane = q). PV as O^T = V^T P^T: P^T re-enters as a B-fragment
// via a tiny LDS round-trip of 4 ds_write_b64 + 2 ds_read_b128 (swizzled, conflict-free).
// Fixed-max softmax (Q pre-scaled by (1/8)log2e), row-sum via ones A-fragment MFMA.
// LDS = 40960 B.
__global__ __launch_bounds__(256) void attn_kernel(const __hip_bfloat16* __restrict__ qkv,
                                                   const __hip_bfloat16* __restrict__ vtg,
                                                   __hip_bfloat16* __restrict__ y) {
  __shared__ __align__(16) __hip_bfloat16 Ks[2][64 * 64];
  __shared__ __align__(16) __hip_bfloat16 Vt[2][64 * 64];
  __shared__ __align__(16) __hip_bfloat16 Pb[4][16 * 64];  // per-wave P[q][k]
  const int tid = threadIdx.x;
  const int lane = tid & 63, wv = tid >> 6;
  const int l15 = lane & 15, quad = lane >> 4;
  const int pt = blockIdx.x, h = blockIdx.y, b = blockIdx.z;
  const int qtA = pt, qtB = 31 - pt;
  const int q0A = qtA * 64, q0B = qtB * 64;
  const long bh = (long)b * 16 + h;
  const long RS = 3072;

  auto issue = [&](int kt, int p) {
    const int kb = kt * 64;
#pragma unroll
    for (int it = 0; it < 2; ++it) {
      const int c = it * 256 + tid;
      const int row = c >> 3;
      const int cg = (c & 7) ^ (row & 7);
      async16(qkv + ((long)b * 2048 + kb + row) * RS + 1024 + h * 64 + cg * 8,
              (char*)&Ks[p][0] + c * 16);
      async16(vtg + (bh * 64 + row) * 2048 + kb + cg * 8, (char*)&Vt[p][0] + c * 16);
    }
  };

  // Q B-fragments for both tiles (B[d][q=l15] == Q[l15][d] -- row-major load)
  bf16x8 bqA0, bqA1, bqB0, bqB1;
  {
    const __hip_bfloat16* qpA = qkv + ((long)b * 2048 + q0A + wv * 16 + l15) * RS + h * 64 + quad * 8;
    bqA0 = *(const bf16x8*)qpA;
    bqA1 = *(const bf16x8*)(qpA + 32);
    const __hip_bfloat16* qpB = qkv + ((long)b * 2048 + q0B + wv * 16 + l15) * RS + h * 64 + quad * 8;
    bqB0 = *(const bf16x8*)qpB;
    bqB1 = *(const bf16x8*)(qpB + 32);
  }
  union { bf16x8 v; __hip_bfloat16 e[8]; } uo;
#pragma unroll
  for (int j = 0; j < 8; ++j) uo.e[j] = __float2bfloat16(1.0f);
  const bf16x8 ones = uo.v;

  floatx4 oA[4] = {}, oB[4] = {}, o4A = {}, o4B = {};
  __hip_bfloat16* Pw = &Pb[wv][0];
  const int m7 = l15 & 7;

  issue(0, 0);
  for (int kt = 0; kt <= qtB; ++kt) {
    const int p = kt & 1;
    const int kb = kt * 64;
    const bool actA = (kt <= qtA);
    __syncthreads();  // drains prefetch into buf p; all waves done reading buf p^1
    if (kt < qtB) issue(kt + 1, p ^ 1);

    // K / V^T fragments from swizzled LDS (shared by both q-tiles)
    bf16x8 kf[4][2], vf[4][2];
#pragma unroll
    for (int nt = 0; nt < 4; ++nt) {
      const int row = nt * 16 + l15;
      const int s0 = (quad ^ (row & 7)) * 8, s1 = ((quad + 4) ^ (row & 7)) * 8;
      kf[nt][0] = *(const bf16x8*)(&Ks[p][row * 64 + s0]);
      kf[nt][1] = *(const bf16x8*)(&Ks[p][row * 64 + s1]);
      vf[nt][0] = *(const bf16x8*)(&Vt[p][row * 64 + s0]);
      vf[nt][1] = *(const bf16x8*)(&Vt[p][row * 64 + s1]);
    }

    auto tile = [&](const bf16x8& bq0, const bf16x8& bq1, floatx4* o, floatx4& o4,
                    bool diag, int q0X) {
      // S^T[k_local=quad*4+r][q=l15]
      floatx4 st[4] = {};
#pragma unroll
      for (int nt = 0; nt < 4; ++nt) {
        st[nt] = MFMA16(kf[nt][0], bq0, st[nt]);
        st[nt] = MFMA16(kf[nt][1], bq1, st[nt]);
      }
      // p = exp2(s), causal mask (k > q) on the diagonal tile; packed b64 stores
      // into P[q=l15][k] with 8-elem-chunk XOR swizzle (phys = chunk ^ (q&7)).
      const int qg = q0X + wv * 16 + l15;
#pragma unroll
      for (int nt = 0; nt < 4; ++nt) {
        union { short4v s; __hip_bfloat16 h[4]; } up;
#pragma unroll
        for (int r = 0; r < 4; ++r) {
          float pv = exp2f(st[nt][r]);
          if (diag && (kb + nt * 16 + quad * 4 + r > qg)) pv = 0.f;
          up.h[r] = __float2bfloat16(pv);
        }
        const int chunk = (nt * 2 + (quad >> 1)) ^ m7;
        *(short4v*)(Pw + l15 * 64 + chunk * 8 + (quad & 1) * 4) = up.s;
      }
      // P^T B-fragments: B[k=quad*8+j][q=l15] = P[l15][quad*8+j]
      const bf16x8 pb0 = *(const bf16x8*)(Pw + l15 * 64 + (quad ^ m7) * 8);
      const bf16x8 pb1 = *(const bf16x8*)(Pw + l15 * 64 + ((quad + 4) ^ m7) * 8);
      // O^T[d][q] += V^T P^T ; l[q] via ones A-frag
#pragma unroll
      for (int mt = 0; mt < 4; ++mt) {
        o[mt] = MFMA16(vf[mt][0], pb0, o[mt]);
        o[mt] = MFMA16(vf[mt][1], pb1, o[mt]);
      }
      o4 = MFMA16(ones, pb0, o4);
      o4 = MFMA16(ones, pb1, o4);
    };

    tile(bqB0, bqB1, oB, o4B, kt == qtB, q0B);
    if (actA) tile(bqA0, bqA1, oA, o4A, kt == qtA, q0A);
  }

  // epilogue: lane holds O^T[d=mt*16+quad*4+r][q=l15]; osum[any r] = l[q]. Packed b64 stores.
  auto epi = [&](floatx4* o, floatx4& o4, int q0X) {
    const float inv = 1.0f / o4[0];
    const long t = (long)b * 2048 + q0X + wv * 16 + l15;
#pragma unroll
    for (int mt = 0; mt < 4; ++mt) {
      union { short4v s; __hip_bfloat16 h[4]; } uy;
#pragma unroll
      for (int r = 0; r < 4; ++r) uy.h[r] = __float2bfloat16(o[mt][r] * inv);
      *(short4v*)(y + t * 1024 + h * 64 + mt * 16 + quad * 4) = uy.s;
    }
  };
  epi(oA, o4A, q0A);
  epi(oB, o4B, q0B);
}

extern "C" void kernel_launch(void* const* d_in, const int* in_sizes, int n_in,
                              void* d_out, int out_size, void* d_ws, size_t ws_size,
                              hipStream_t stream) {
  const float* x      = (const float*)d_in[0];
  const float* w_attn = (const float*)d_in[1];
  const float* w_proj = (const float*)d_in[2];
  float* out = (float*)d_out;
  char* ws = (char*)d_ws;
  __hip_bfloat16* xb   = (__hip_bfloat16*)(ws);               // then vt
  __hip_bfloat16* wat  = (__hip_bfloat16*)(ws + 8388608);     // then yb
  __hip_bfloat16* qkvb = (__hip_bfloat16*)(ws + 16777216);
  __hip_bfloat16* wpt  = (__hip_bfloat16*)(ws + 41943040);
  __hip_bfloat16* vtg  = xb;
  __hip_bfloat16* yb   = wat;
  const float SC = 0.18033688011112042f;  // (1/8) * log2(e)

  // prep: cast x (4096 blocks) + transpose w_attn (3072) + transpose w_proj (1024)
  prep_kernel<<<8192, 256, 0, stream>>>(x, w_attn, w_proj, xb, wat, wpt);
  // qkv = x @ w_attn, Q columns pre-scaled by SC
  gemm_bt_kernel<__hip_bfloat16><<<dim3(24, 32), 256, 0, stream>>>(xb, wat, qkvb, 4096, 3072, 1024, SC, 1024);
  // V^T (overwrites xb -- dead after the qkv GEMM)
  vt_kernel<<<dim3(32, 16, 2), 256, 0, stream>>>(qkvb, vtg);
  // attention (writes yb over wat -- dead after the qkv GEMM)
  attn_kernel<<<dim3(16, 16, 2), 256, 0, stream>>>(qkvb, vtg, yb);
  // out = y @ w_proj
  gemm_bt64_kernel<float><<<dim3(16, 32), 256, 0, stream>>>(yb, wpt, out, 4096, 1024, 1024);
}

// Round 7
// 181.988 us; speedup vs baseline: 1.2865x; 1.0228x over previous
//
#include <hip/hip_runtime.h>
#include <hip/hip_bf16.h>

// B=2, T=2048, C=1024, H=16, Dh=64
// ws layout (bytes), total 43,646,976 (qkv holds Q,K only; V goes straight to vt):
//   xb   [4096x1024] bf16 @ 0          (8 MB)
//   wat  [3072x1024] bf16 @ 8388608    (6 MB) -- reused as yb [4096x1024] after qkv GEMM
//   qk   [4096x2048] bf16 @ 16777216   (16 MB; Q cols pre-scaled by (1/8)log2e)
//   wpt  [1024x1024] bf16 @ 33554432   (2 MB)
//   vt   [2][16][64][2048] bf16 @ 35651584 (8 MB)

typedef __attribute__((ext_vector_type(8))) __bf16 bf16x8;
typedef __attribute__((ext_vector_type(4))) float  floatx4;
typedef __attribute__((ext_vector_type(4))) float  fvec4;
typedef __attribute__((ext_vector_type(4))) short  short4v;

#define MFMA16(a, b, c) __builtin_amdgcn_mfma_f32_16x16x32_bf16(a, b, c, 0, 0, 0)

using as1v = const __attribute__((address_space(1))) void;
using as3v = __attribute__((address_space(3))) void;
__device__ __forceinline__ void async16(const void* g, void* l) {
  __builtin_amdgcn_global_load_lds((as1v*)g, (as3v*)l, 16, 0, 0);
}

__device__ inline void store_out(float* p, float v) { *p = v; }
__device__ inline void store_out(__hip_bfloat16* p, float v) { *p = __float2bfloat16(v); }

// ---------------- fused prep: cast x; 64x64 vectorized transpose+cast of weights ----------------
__global__ __launch_bounds__(256) void prep_kernel(const float* __restrict__ x,
                                                   const float* __restrict__ w_attn,
                                                   const float* __restrict__ w_proj,
                                                   __hip_bfloat16* __restrict__ xb,
                                                   __hip_bfloat16* __restrict__ wat,
                                                   __hip_bfloat16* __restrict__ wpt) {
  const int bid = blockIdx.x, tid = threadIdx.x;
  if (bid < 4096) {  // cast x -> bf16 (4 elems/thread)
    const int i = (bid * 256 + tid) * 4;
    fvec4 v = *(const fvec4*)(x + i);
    union { short4v s; __hip_bfloat16 h[4]; } u;
#pragma unroll
    for (int j = 0; j < 4; ++j) u.h[j] = __float2bfloat16(v[j]);
    *(short4v*)((short*)xb + i) = u.s;
    return;
  }
  __shared__ __align__(16) __hip_bfloat16 tile[64 * 64];
  const float* in;
  __hip_bfloat16* out;
  int cols, bx, by;
  if (bid < 4864) {
    const int b2 = bid - 4096;
    in = w_attn; out = wat; cols = 3072; bx = b2 % 48; by = b2 / 48;
  } else {
    const int b2 = bid - 4864;
    in = w_proj; out = wpt; cols = 1024; bx = b2 % 16; by = b2 / 16;
  }
  const int c0 = bx * 64, r0 = by * 64;  // input rows = 1024
#pragma unroll
  for (int it = 0; it < 2; ++it) {
    const int c = it * 256 + tid;
    const int row = c >> 3, cg = c & 7;
    const float* src = in + (long)(r0 + row) * cols + c0 + cg * 8;
    fvec4 v0 = *(const fvec4*)src;
    fvec4 v1 = *(const fvec4*)(src + 4);
    union { bf16x8 v; __hip_bfloat16 h[8]; } u;
#pragma unroll
    for (int j = 0; j < 4; ++j) { u.h[j] = __float2bfloat16(v0[j]); u.h[4 + j] = __float2bfloat16(v1[j]); }
    *(bf16x8*)(tile + row * 64 + (cg ^ ((row >> 3) & 7)) * 8) = u.v;
  }
  __syncthreads();
#pragma unroll
  for (int it = 0; it < 2; ++it) {
    const int c = it * 256 + tid;
    const int dr = c >> 3, tg = c & 7;
    union { bf16x8 v; __hip_bfloat16 e[8]; } u;
    const int pg = (dr >> 3) ^ tg;
#pragma unroll
    for (int j = 0; j < 8; ++j)
      u.e[j] = tile[(tg * 8 + j) * 64 + pg * 8 + (dr & 7)];
    *(bf16x8*)(out + (long)(c0 + dr) * 1024 + r0 + tg * 8) = u.v;
  }
}

// ------------- qkv GEMM: A[4096,1024] x wat^T -> qk[4096,2048] + vt (V transposed) -------------
__global__ __launch_bounds__(256) void gemm_qkv_kernel(const __hip_bfloat16* __restrict__ A,
                                                       const __hip_bfloat16* __restrict__ Bt,
                                                       __hip_bfloat16* __restrict__ qk,
                                                       __hip_bfloat16* __restrict__ vt,
                                                       float qscale) {
  const int K = 1024;
  __shared__ __align__(16) __hip_bfloat16 As[2][128 * 32];
  __shared__ __align__(16) __hip_bfloat16 Bs[2][128 * 32];
  const int tid = threadIdx.x;
  const int lane = tid & 63, wv = tid >> 6;
  const int l15 = lane & 15, quad = lane >> 4;
  const int wm = wv >> 1, wn = wv & 1;
  const long m0 = (long)blockIdx.y * 128, n0 = (long)blockIdx.x * 128;
  floatx4 acc[4][4] = {};
  const int nk = K >> 5;

  auto issue = [&](int kt, int p) {
    const int k0 = kt << 5;
#pragma unroll
    for (int it = 0; it < 2; ++it) {
      const int c = it * 256 + tid;
      const int row = c >> 2;
      const int lcg = (c & 3) ^ ((row >> 1) & 3);
      async16(A + (m0 + row) * K + k0 + lcg * 8, (char*)&As[p][0] + c * 16);
      async16(Bt + (n0 + row) * K + k0 + lcg * 8, (char*)&Bs[p][0] + c * 16);
    }
  };

  issue(0, 0);
  for (int kt = 0; kt < nk; ++kt) {
    const int p = kt & 1;
    __syncthreads();
    if (kt + 1 < nk) issue(kt + 1, p ^ 1);
    bf16x8 af[4], bfr[4];
#pragma unroll
    for (int t = 0; t < 4; ++t) {
      const int ar = wm * 64 + t * 16 + l15;
      const int br = wn * 64 + t * 16 + l15;
      af[t]  = *(const bf16x8*)(&As[p][ar * 32 + (quad ^ ((ar >> 1) & 3)) * 8]);
      bfr[t] = *(const bf16x8*)(&Bs[p][br * 32 + (quad ^ ((br >> 1) & 3)) * 8]);
    }
#pragma unroll
    for (int mt = 0; mt < 4; ++mt)
#pragma unroll
      for (int nt = 0; nt < 4; ++nt)
        acc[mt][nt] = MFMA16(af[mt], bfr[nt], acc[mt][nt]);
  }

#pragma unroll
  for (int nt = 0; nt < 4; ++nt) {
    const int colb = (int)n0 + wn * 64 + nt * 16;  // wave-uniform, multiple of 16
    if (colb >= 2048) {
      const int hh = (colb - 2048) >> 6;
      const int d  = (colb & 63) + l15;
#pragma unroll
      for (int mt = 0; mt < 4; ++mt) {
        const long row = m0 + wm * 64 + mt * 16 + quad * 4;
        const long b   = row >> 11;
        const long t0  = row & 2047;
        union { short4v s; __hip_bfloat16 h[4]; } uy;
#pragma unroll
        for (int r = 0; r < 4; ++r) uy.h[r] = __float2bfloat16(acc[mt][nt][r]);
        *(short4v*)(vt + ((b * 16 + hh) * 64 + d) * 2048 + t0) = uy.s;
      }
    } else {
      const float sc = (colb < 1024) ? qscale : 1.0f;
      const long col = colb + l15;
#pragma unroll
      for (int mt = 0; mt < 4; ++mt)
#pragma unroll
        for (int r = 0; r < 4; ++r) {
          const long row = m0 + wm * 64 + mt * 16 + quad * 4 + r;
          qk[row * 2048 + col] = __float2bfloat16(acc[mt][nt][r] * sc);
        }
    }
  }
}

// ------------- GEMM 128x64 (proj) -------------
template <typename OutT>
__global__ __launch_bounds__(256) void gemm_bt64_kernel(const __hip_bfloat16* __restrict__ A,
                                                        const __hip_bfloat16* __restrict__ Bt,
                                                        OutT* __restrict__ C,
                                                        int M, int N, int K) {
  __shared__ __align__(16) __hip_bfloat16 As[2][128 * 32];
  __shared__ __align__(16) __hip_bfloat16 Bs[2][64 * 32];
  const int tid = threadIdx.x;
  const int lane = tid & 63, wv = tid >> 6;
  const int l15 = lane & 15, quad = lane >> 4;
  const int wm = wv >> 1, wn = wv & 1;
  const long m0 = (long)blockIdx.y * 128, n0 = (long)blockIdx.x * 64;
  floatx4 acc[4][2] = {};
  const int nk = K >> 5;

  auto issue = [&](int kt, int p) {
    const int k0 = kt << 5;
#pragma unroll
    for (int it = 0; it < 2; ++it) {
      const int c = it * 256 + tid;
      const int row = c >> 2;
      const int lcg = (c & 3) ^ ((row >> 1) & 3);
      async16(A + (m0 + row) * K + k0 + lcg * 8, (char*)&As[p][0] + c * 16);
    }
    {
      const int c = tid;
      const int row = c >> 2;
      const int lcg = (c & 3) ^ ((row >> 1) & 3);
      async16(Bt + (n0 + row) * K + k0 + lcg * 8, (char*)&Bs[p][0] + c * 16);
    }
  };

  issue(0, 0);
  for (int kt = 0; kt < nk; ++kt) {
    const int p = kt & 1;
    __syncthreads();
    if (kt + 1 < nk) issue(kt + 1, p ^ 1);
    bf16x8 af[4], bfr[2];
#pragma unroll
    for (int t = 0; t < 4; ++t) {
      const int ar = wm * 64 + t * 16 + l15;
      af[t] = *(const bf16x8*)(&As[p][ar * 32 + (quad ^ ((ar >> 1) & 3)) * 8]);
    }
#pragma unroll
    for (int t = 0; t < 2; ++t) {
      const int br = wn * 32 + t * 16 + l15;
      bfr[t] = *(const bf16x8*)(&Bs[p][br * 32 + (quad ^ ((br >> 1) & 3)) * 8]);
    }
#pragma unroll
    for (int mt = 0; mt < 4; ++mt)
#pragma unroll
      for (int nt = 0; nt < 2; ++nt)
        acc[mt][nt] = MFMA16(af[mt], bfr[nt], acc[mt][nt]);
  }
#pragma unroll
  for (int mt = 0; mt < 4; ++mt)
#pragma unroll
    for (int nt = 0; nt < 2; ++nt)
#pragma unroll
      for (int r = 0; r < 4; ++r) {
        const long row = m0 + wm * 64 + mt * 16 + quad * 4 + r;
        const long col = n0 + wn * 32 + nt * 16 + l15;
        store_out(C + row * N + col, acc[mt][nt][r]);
      }
}

// ------------- paired-tile flash attention (qk buffer now [4096][2048], K at +1024) -------------
__global__ __launch_bounds__(256) void attn_kernel(const __hip_bfloat16* __restrict__ qk,
                                                   const __hip_bfloat16* __restrict__ vtg,
                                                   __hip_bfloat16* __restrict__ y) {
  __shared__ __align__(16) __hip_bfloat16 Ks[2][64 * 64];
  __shared__ __align__(16) __hip_bfloat16 Vt[2][64 * 64];
  __shared__ __align__(16) __hip_bfloat16 Pb[4][16 * 64];  // per-wave P[q][k]
  const int tid = threadIdx.x;
  const int lane = tid & 63, wv = tid >> 6;
  const int l15 = lane & 15, quad = lane >> 4;
  const int pt = blockIdx.x, h = blockIdx.y, b = blockIdx.z;
  const int qtA = pt, qtB = 31 - pt;
  const int q0A = qtA * 64, q0B = qtB * 64;
  const long bh = (long)b * 16 + h;
  const long RS = 2048;

  auto issue = [&](int kt, int p) {
    const int kb = kt * 64;
#pragma unroll
    for (int it = 0; it < 2; ++it) {
      const int c = it * 256 + tid;
      const int row = c >> 3;
      const int cg = (c & 7) ^ (row & 7);
      async16(qk + ((long)b * 2048 + kb + row) * RS + 1024 + h * 64 + cg * 8,
              (char*)&Ks[p][0] + c * 16);
      async16(vtg + (bh * 64 + row) * 2048 + kb + cg * 8, (char*)&Vt[p][0] + c * 16);
    }
  };

  bf16x8 bqA0, bqA1, bqB0, bqB1;
  {
    const __hip_bfloat16* qpA = qk + ((long)b * 2048 + q0A + wv * 16 + l15) * RS + h * 64 + quad * 8;
    bqA0 = *(const bf16x8*)qpA;
    bqA1 = *(const bf16x8*)(qpA + 32);
    const __hip_bfloat16* qpB = qk + ((long)b * 2048 + q0B + wv * 16 + l15) * RS + h * 64 + quad * 8;
    bqB0 = *(const bf16x8*)qpB;
    bqB1 = *(const bf16x8*)(qpB + 32);
  }
  union { bf16x8 v; __hip_bfloat16 e[8]; } uo;
#pragma unroll
  for (int j = 0; j < 8; ++j) uo.e[j] = __float2bfloat16(1.0f);
  const bf16x8 ones = uo.v;

  floatx4 oA[4] = {}, oB[4] = {}, o4A = {}, o4B = {};
  __hip_bfloat16* Pw = &Pb[wv][0];
  const int m7 = l15 & 7;

  issue(0, 0);
  for (int kt = 0; kt <= qtB; ++kt) {
    const int p = kt & 1;
    const int kb = kt * 64;
    const bool actA = (kt <= qtA);
    __syncthreads();
    if (kt < qtB) issue(kt + 1, p ^ 1);

    bf16x8 kf[4][2], vf[4][2];
#pragma unroll
    for (int nt = 0; nt < 4; ++nt) {
      const int row = nt * 16 + l15;
      const int s0 = (quad ^ (row & 7)) * 8, s1 = ((quad + 4) ^ (row & 7)) * 8;
      kf[nt][0] = *(const bf16x8*)(&Ks[p][row * 64 + s0]);
      kf[nt][1] = *(const bf16x8*)(&Ks[p][row * 64 + s1]);
      vf[nt][0] = *(const bf16x8*)(&Vt[p][row * 64 + s0]);
      vf[nt][1] = *(const bf16x8*)(&Vt[p][row * 64 + s1]);
    }

    auto tile = [&](const bf16x8& bq0, const bf16x8& bq1, floatx4* o, floatx4& o4,
                    bool diag, int q0X) {
      floatx4 st[4] = {};
#pragma unroll
      for (int nt = 0; nt < 4; ++nt) {
        st[nt] = MFMA16(kf[nt][0], bq0, st[nt]);
        st[nt] = MFMA16(kf[nt][1], bq1, st[nt]);
      }
      const int qg = q0X + wv * 16 + l15;
#pragma unroll
      for (int nt = 0; nt < 4; ++nt) {
        union { short4v s; __hip_bfloat16 h[4]; } up;
#pragma unroll
        for (int r = 0; r < 4; ++r) {
          float pv = exp2f(st[nt][r]);
          if (diag && (kb + nt * 16 + quad * 4 + r > qg)) pv = 0.f;
          up.h[r] = __float2bfloat16(pv);
        }
        const int chunk = (nt * 2 + (quad >> 1)) ^ m7;
        *(short4v*)(Pw + l15 * 64 + chunk * 8 + (quad & 1) * 4) = up.s;
      }
      const bf16x8 pb0 = *(const bf16x8*)(Pw + l15 * 64 + (quad ^ m7) * 8);
      const bf16x8 pb1 = *(const bf16x8*)(Pw + l15 * 64 + ((quad + 4) ^ m7) * 8);
#pragma unroll
      for (int mt = 0; mt < 4; ++mt) {
        o[mt] = MFMA16(vf[mt][0], pb0, o[mt]);
        o[mt] = MFMA16(vf[mt][1], pb1, o[mt]);
      }
      o4 = MFMA16(ones, pb0, o4);
      o4 = MFMA16(ones, pb1, o4);
    };

    tile(bqB0, bqB1, oB, o4B, kt == qtB, q0B);
    if (actA) tile(bqA0, bqA1, oA, o4A, kt == qtA, q0A);
  }

  auto epi = [&](floatx4* o, floatx4& o4, int q0X) {
    const float inv = 1.0f / o4[0];
    const long t = (long)b * 2048 + q0X + wv * 16 + l15;
#pragma unroll
    for (int mt = 0; mt < 4; ++mt) {
      union { short4v s; __hip_bfloat16 h[4]; } uy;
#pragma unroll
      for (int r = 0; r < 4; ++r) uy.h[r] = __float2bfloat16(o[mt][r] * inv);
      *(short4v*)(y + t * 1024 + h * 64 + mt * 16 + quad * 4) = uy.s;
    }
  };
  epi(oA, o4A, q0A);
  epi(oB, o4B, q0B);
}

extern "C" void kernel_launch(void* const* d_in, const int* in_sizes, int n_in,
                              void* d_out, int out_size, void* d_ws, size_t ws_size,
                              hipStream_t stream) {
  const float* x      = (const float*)d_in[0];
  const float* w_attn = (const float*)d_in[1];
  const float* w_proj = (const float*)d_in[2];
  float* out = (float*)d_out;
  char* ws = (char*)d_ws;
  __hip_bfloat16* xb  = (__hip_bfloat16*)(ws);
  __hip_bfloat16* wat = (__hip_bfloat16*)(ws + 8388608);    // reused as yb after qkv GEMM
  __hip_bfloat16* qk  = (__hip_bfloat16*)(ws + 16777216);   // [4096][2048] Q|K
  __hip_bfloat16* wpt = (__hip_bfloat16*)(ws + 33554432);
  __hip_bfloat16* vtg = (__hip_bfloat16*)(ws + 35651584);   // [2][16][64][2048]
  __hip_bfloat16* yb  = wat;
  const float SC = 0.18033688011112042f;  // (1/8) * log2(e)

  // prep: cast x (4096) + transpose w_attn (768) + transpose w_proj (256)
  prep_kernel<<<5120, 256, 0, stream>>>(x, w_attn, w_proj, xb, wat, wpt);
  // qkv GEMM: writes Q(prescaled),K into qk and V transposed into vtg
  gemm_qkv_kernel<<<dim3(24, 32), 256, 0, stream>>>(xb, wat, qk, vtg, SC);
  // attention (writes yb over wat -- dead after the qkv GEMM)
  attn_kernel<<<dim3(16, 16, 2), 256, 0, stream>>>(qk, vtg, yb);
  // out = y @ w_proj
  gemm_bt64_kernel<float><<<dim3(16, 32), 256, 0, stream>>>(yb, wpt, out, 4096, 1024, 1024);
}